// Round 1
// baseline (285.137 us; speedup 1.0000x reference)
//
#include <hip/hip_runtime.h>
#include <cstddef>

// AttentionLayerPooler: out[m,n] = sum_l softmax(logits)[m,l] * in[l,n]
// for in = ks and vs separately. L_TEACHER=36, L_STUDENT=28,
// per-layer slice = B*H*S*D = 1*16*1024*128 = 2,097,152 fp32.
// Memory-bound: 1.07 GB total traffic -> ~170 us floor @ 6.3 TB/s.

constexpr int LT = 36;                      // teacher layers
constexpr int LS = 28;                      // student layers
constexpr int NELEM = 1 * 16 * 1024 * 128;  // elements per layer slice
constexpr int N4 = NELEM / 4;               // float4 columns per layer (524288)
constexpr int TPB = 256;
constexpr int BLOCKS_PER_TENSOR = N4 / TPB; // 2048 (power of two)

__device__ __forceinline__ void fma4(float4& a, float w, const float4& v) {
    a.x = fmaf(w, v.x, a.x);
    a.y = fmaf(w, v.y, a.y);
    a.z = fmaf(w, v.z, a.z);
    a.w = fmaf(w, v.w, a.w);
}

__global__ __launch_bounds__(TPB) void pool_kernel(
    const float4* __restrict__ ks,
    const float4* __restrict__ vs,
    const float* __restrict__ lgk,
    const float* __restrict__ lgv,
    float4* __restrict__ out)
{
    // Per-block softmax of the 28x36 weight matrix into LDS.
    // Rows are 36 floats = 144 B -> 16B-aligned, so float4 reads along l work.
    __shared__ __align__(16) float wl[LS][LT];

    const bool is_v = (blockIdx.x >= BLOCKS_PER_TENSOR);
    const float* lg = is_v ? lgv : lgk;
    const float4* src = is_v ? vs : ks;
    float4* dst = out + (is_v ? (size_t)LS * N4 : (size_t)0);

    const int tid = threadIdx.x;
    if (tid < LS) {
        const float* row = lg + tid * LT;
        float mx = -3.4e38f;
        for (int l = 0; l < LT; ++l) mx = fmaxf(mx, row[l]);
        float s = 0.f;
        for (int l = 0; l < LT; ++l) s += expf(row[l] - mx);
        const float inv = 1.0f / s;
        for (int l = 0; l < LT; ++l) wl[tid][l] = expf(row[l] - mx) * inv;
    }
    __syncthreads();

    // Each thread owns one float4 column; loads all 36 layers once,
    // accumulates all 28 outputs in registers (112 VGPRs of acc).
    const int n4 = (blockIdx.x & (BLOCKS_PER_TENSOR - 1)) * TPB + tid;
    const float4* p = src + n4;

    float4 acc[LS];
#pragma unroll
    for (int m = 0; m < LS; ++m) acc[m] = make_float4(0.f, 0.f, 0.f, 0.f);

#pragma unroll 3
    for (int lb = 0; lb < LT / 4; ++lb) {
        const float4 v0 = p[(size_t)(4 * lb + 0) * N4];
        const float4 v1 = p[(size_t)(4 * lb + 1) * N4];
        const float4 v2 = p[(size_t)(4 * lb + 2) * N4];
        const float4 v3 = p[(size_t)(4 * lb + 3) * N4];
#pragma unroll
        for (int m = 0; m < LS; ++m) {
            const float4 w = *reinterpret_cast<const float4*>(&wl[m][4 * lb]);
            fma4(acc[m], w.x, v0);
            fma4(acc[m], w.y, v1);
            fma4(acc[m], w.z, v2);
            fma4(acc[m], w.w, v3);
        }
    }

    float4* q = dst + n4;
#pragma unroll
    for (int m = 0; m < LS; ++m) q[(size_t)m * N4] = acc[m];
}

extern "C" void kernel_launch(void* const* d_in, const int* in_sizes, int n_in,
                              void* d_out, int out_size, void* d_ws, size_t ws_size,
                              hipStream_t stream)
{
    const float4* ks  = (const float4*)d_in[0];
    const float4* vs  = (const float4*)d_in[1];
    const float* lgk  = (const float*)d_in[2];
    const float* lgv  = (const float*)d_in[3];
    float4* out = (float4*)d_out;

    dim3 grid(2 * BLOCKS_PER_TENSOR);
    dim3 block(TPB);
    hipLaunchKernelGGL(pool_kernel, grid, block, 0, stream,
                       ks, vs, lgk, lgv, out);
}